// Round 1
// baseline (322.407 us; speedup 1.0000x reference)
//
#include <hip/hip_runtime.h>
#include <math.h>

#define B_    2
#define S_    512
#define HDIM  1024
#define D_    24      // proj dim
#define M_    96      // pair-MLP hidden
#define ROWS  (B_*S_) // 1024

// ---------------------------------------------------------------------------
// K1: Zj = H_j @ p_j, Zi = H_i @ p_i   -> [ROWS][24]
// one wave per row
// ---------------------------------------------------------------------------
__global__ __launch_bounds__(64) void proj_kernel(
    const float* __restrict__ Hj, const float* __restrict__ Hi,
    const float* __restrict__ pj, const float* __restrict__ pi,
    float* __restrict__ Zj, float* __restrict__ Zi) {
  int r = blockIdx.x;
  int lane = threadIdx.x;
  const float* hj = Hj + (size_t)r * HDIM;
  const float* hi = Hi + (size_t)r * HDIM;
  float accj[D_], acci[D_];
#pragma unroll
  for (int d = 0; d < D_; ++d) { accj[d] = 0.f; acci[d] = 0.f; }
  for (int k = lane; k < HDIM; k += 64) {
    float a = hj[k], b = hi[k];
    const float* pjr = pj + k * D_;
    const float* pir = pi + k * D_;
#pragma unroll
    for (int d = 0; d < D_; ++d) {
      accj[d] = fmaf(a, pjr[d], accj[d]);
      acci[d] = fmaf(b, pir[d], acci[d]);
    }
  }
#pragma unroll
  for (int d = 0; d < D_; ++d) {
    for (int off = 32; off > 0; off >>= 1) {
      accj[d] += __shfl_down(accj[d], off, 64);
      acci[d] += __shfl_down(acci[d], off, 64);
    }
  }
  if (lane == 0) {
#pragma unroll
    for (int d = 0; d < D_; ++d) {
      Zj[r * D_ + d] = accj[d];
      Zi[r * D_ + d] = acci[d];
    }
  }
}

// ---------------------------------------------------------------------------
// K2: Aj[r][m] = b1[m] + sum_d Zj[r][d]*W1[d][m]          (Zj-part of W1)
//     BiT[m][r] =        sum_d Zi[r][d]*W1[24+d][m]       (Zi-part, transposed)
// ---------------------------------------------------------------------------
__global__ __launch_bounds__(128) void ab_kernel(
    const float* __restrict__ Zj, const float* __restrict__ Zi,
    const float* __restrict__ W1, const float* __restrict__ b1,
    float* __restrict__ Aj, float* __restrict__ BiT) {
  int r = blockIdx.x;
  int m = threadIdx.x;
  __shared__ float zj[D_], zi[D_];
  if (m < D_) { zj[m] = Zj[r * D_ + m]; zi[m] = Zi[r * D_ + m]; }
  __syncthreads();
  if (m < M_) {
    float aj = b1[m], bi = 0.f;
#pragma unroll
    for (int d = 0; d < D_; ++d) {
      aj = fmaf(zj[d], W1[d * M_ + m], aj);
      bi = fmaf(zi[d], W1[(D_ + d) * M_ + m], bi);
    }
    Aj[r * M_ + m] = aj;
    BiT[(size_t)m * ROWS + r] = bi;
  }
}

// ---------------------------------------------------------------------------
// K3: per (b, pair of j rows): logits over all 512 i via split pair-MLP,
//     masked softmax, write probs [B,S,S]
// block = 512 threads (8 waves), grid = 512. jj = t/256, ii = t%256
// ---------------------------------------------------------------------------
__global__ __launch_bounds__(512) void pair_softmax_kernel(
    const float* __restrict__ Zj, const float* __restrict__ Zi,
    const float* __restrict__ Aj, const float* __restrict__ BiT,
    const float* __restrict__ W1, const float* __restrict__ W2,
    const float* __restrict__ mask, float* __restrict__ probs) {
  __shared__ float Wct[M_ * D_];   // [m][d] weights for Zj*Zi term
  __shared__ float Wdt[M_ * D_];   // [m][d] weights for |Zj-Zi| term
  __shared__ float W2s[M_];
  __shared__ float zjL[2][D_];
  __shared__ float AjL[2][M_];
  __shared__ float logitsL[2][S_];
  __shared__ float red[16];

  int t = threadIdx.x;
  int bj = blockIdx.x;           // 0..511
  int b = bj >> 8;
  int j0 = (bj & 255) * 2;
  int rj0 = b * S_ + j0;

  for (int idx = t; idx < M_ * D_; idx += 512) {
    int m = idx / D_, d = idx - m * D_;
    Wct[idx] = W1[(2 * D_ + d) * M_ + m];
    Wdt[idx] = W1[(3 * D_ + d) * M_ + m];
  }
  if (t < M_) W2s[t] = W2[t];
  if (t < 2 * D_) zjL[t / D_][t % D_] = Zj[(rj0 + t / D_) * D_ + (t % D_)];
  if (t < 2 * M_) AjL[t / M_][t % M_] = Aj[(rj0 + t / M_) * M_ + (t % M_)];
  __syncthreads();

  int jj = t >> 8;       // 0..1
  int ii = t & 255;

  float zj[D_];
#pragma unroll
  for (int d = 0; d < D_; ++d) zj[d] = zjL[jj][d];

  for (int istep = 0; istep < 2; ++istep) {
    int i = istep * 256 + ii;
    const float* zir = Zi + (size_t)(b * S_ + i) * D_;
    float prod[D_], adiff[D_];
#pragma unroll
    for (int d = 0; d < D_; ++d) {
      float z = zir[d];
      prod[d] = zj[d] * z;
      adiff[d] = fabsf(zj[d] - z);
    }
    float acc = 0.f;
    const float* bit = BiT + (b * S_ + i);
#pragma unroll 2
    for (int m = 0; m < M_; ++m) {
      float h = AjL[jj][m] + bit[(size_t)m * ROWS];
      const float* wc = &Wct[m * D_];
      const float* wd = &Wdt[m * D_];
#pragma unroll
      for (int d = 0; d < D_; ++d) {
        h = fmaf(prod[d], wc[d], h);
        h = fmaf(adiff[d], wd[d], h);
      }
      acc = fmaf(fmaxf(h, 0.f), W2s[m], acc);
    }
    // additive key-side mask (b2 omitted: softmax shift-invariant)
    float lg = acc + (1.0f - mask[b * S_ + i]) * (-3.40282347e38f);
    logitsL[jj][i] = lg;
  }
  __syncthreads();

  // softmax per row over 512 keys; 4 waves per row, 2 elems per lane
  int w = t >> 6, lane = t & 63;
  int row = w >> 2, q = w & 3;
  int i1 = q * 64 + lane;
  int i2 = i1 + 256;
  float l1 = logitsL[row][i1], l2 = logitsL[row][i2];
  float mx = fmaxf(l1, l2);
#pragma unroll
  for (int off = 32; off > 0; off >>= 1) mx = fmaxf(mx, __shfl_down(mx, off, 64));
  if (lane == 0) red[w] = mx;
  __syncthreads();
  float rmax = fmaxf(fmaxf(red[row * 4 + 0], red[row * 4 + 1]),
                     fmaxf(red[row * 4 + 2], red[row * 4 + 3]));
  float e1 = __expf(l1 - rmax);
  float e2 = __expf(l2 - rmax);
  float s = e1 + e2;
#pragma unroll
  for (int off = 32; off > 0; off >>= 1) s += __shfl_down(s, off, 64);
  if (lane == 0) red[8 + w] = s;
  __syncthreads();
  float rsum = red[8 + row * 4 + 0] + red[8 + row * 4 + 1] +
               red[8 + row * 4 + 2] + red[8 + row * 4 + 3];
  float inv = 1.0f / rsum;
  size_t base = (size_t)(rj0 + row) * S_;
  probs[base + i1] = e1 * inv;
  probs[base + i2] = e2 * inv;
}

// ---------------------------------------------------------------------------
// Generic fp32 tiled GEMM: C = epilogue( [A0|A1] @ B + bias )
// A row-major (lda = K0 / K1), B row-major [K0+K1][N], 64x64 tile, BK=16,
// 256 threads, 4x4 per thread. All dims multiples of tile sizes here.
// ---------------------------------------------------------------------------
template <bool RELU, bool FINAL>
__global__ __launch_bounds__(256) void gemm_kernel(
    const float* __restrict__ A0, const float* __restrict__ A1,
    const float* __restrict__ Bm, const float* __restrict__ bias,
    const float* __restrict__ alpha_ptr, float* __restrict__ C,
    int M, int N, int K0, int K1,
    long aB0, long aB1, long bB, long cB) {
  __shared__ float As[16][68];   // [k][m], padded
  __shared__ float Bs[16][64];   // [k][n]
  int t = threadIdx.x;
  int tx = t & 15, ty = t >> 4;
  int n0 = blockIdx.x * 64, m0 = blockIdx.y * 64, bb = blockIdx.z;
  const float* A0b = A0 + (size_t)bb * aB0;
  const float* A1b = A1 ? A1 + (size_t)bb * aB1 : nullptr;
  const float* Bb  = Bm + (size_t)bb * bB;
  float acc[4][4] = {};
  int lr = t >> 2;           // A-load row 0..63
  int lc = (t & 3) * 4;      // A-load k 0,4,8,12
  int bk = t >> 4;           // B-load k 0..15
  int bn = (t & 15) * 4;     // B-load n
  int K = K0 + K1;
  for (int kt = 0; kt < K; kt += 16) {
    const float* arow;
    if (kt < K0) arow = A0b + (size_t)(m0 + lr) * K0 + kt + lc;
    else         arow = A1b + (size_t)(m0 + lr) * K1 + (kt - K0) + lc;
    float4 av = *(const float4*)arow;
    As[lc + 0][lr] = av.x; As[lc + 1][lr] = av.y;
    As[lc + 2][lr] = av.z; As[lc + 3][lr] = av.w;
    float4 bv = *(const float4*)(Bb + (size_t)(kt + bk) * N + n0 + bn);
    *(float4*)&Bs[bk][bn] = bv;
    __syncthreads();
#pragma unroll
    for (int kk = 0; kk < 16; ++kk) {
      float4 a4 = *(const float4*)&As[kk][ty * 4];
      float4 b4 = *(const float4*)&Bs[kk][tx * 4];
      float a_[4] = {a4.x, a4.y, a4.z, a4.w};
      float b_[4] = {b4.x, b4.y, b4.z, b4.w};
#pragma unroll
      for (int u = 0; u < 4; ++u)
#pragma unroll
        for (int v = 0; v < 4; ++v)
          acc[u][v] = fmaf(a_[u], b_[v], acc[u][v]);
    }
    __syncthreads();
  }
  float alpha = 1.0f;
  if (FINAL) alpha = *alpha_ptr;
  size_t cbase = (size_t)bb * cB;
#pragma unroll
  for (int u = 0; u < 4; ++u) {
    int gr = m0 + ty * 4 + u;
    float4 o;
    float ov[4];
#pragma unroll
    for (int v = 0; v < 4; ++v) {
      int gc = n0 + tx * 4 + v;
      float x = acc[u][v];
      if (bias) x += bias[gc];
      if (RELU) x = fmaxf(x, 0.f);
      if (FINAL) x *= alpha;
      ov[v] = x;
    }
    o.x = ov[0]; o.y = ov[1]; o.z = ov[2]; o.w = ov[3];
    *(float4*)&C[cbase + (size_t)gr * N + n0 + tx * 4] = o;
  }
}

// ---------------------------------------------------------------------------
extern "C" void kernel_launch(void* const* d_in, const int* in_sizes, int n_in,
                              void* d_out, int out_size, void* d_ws, size_t ws_size,
                              hipStream_t stream) {
  const float* Hj   = (const float*)d_in[0];
  const float* Hi   = (const float*)d_in[1];
  const float* mask = (const float*)d_in[2];
  const float* pj   = (const float*)d_in[3];
  const float* pi   = (const float*)d_in[4];
  const float* W1   = (const float*)d_in[5];
  const float* b1   = (const float*)d_in[6];
  const float* W2   = (const float*)d_in[7];
  // d_in[8] = b2: uniform over keys -> softmax invariant, unused
  const float* Wv1  = (const float*)d_in[9];
  const float* bv1  = (const float*)d_in[10];
  const float* Wv2  = (const float*)d_in[11];
  const float* bv2  = (const float*)d_in[12];
  const float* alpha = (const float*)d_in[13];

  float* ws = (float*)d_ws;
  float* Zj     = ws;                  // 1024*24
  float* Zi     = Zj + ROWS * D_;      // 1024*24
  float* Aj     = Zi + ROWS * D_;      // 1024*96
  float* BiT    = Aj + ROWS * M_;      // 96*1024
  float* probs  = BiT + M_ * ROWS;     // 2*512*512
  float* ctx    = probs + (size_t)B_ * S_ * S_;   // 1024*1024
  float* hidden = ctx + (size_t)ROWS * HDIM;      // 1024*1024
  float* out = (float*)d_out;

  proj_kernel<<<ROWS, 64, 0, stream>>>(Hj, Hi, pj, pi, Zj, Zi);
  ab_kernel<<<ROWS, 128, 0, stream>>>(Zj, Zi, W1, b1, Aj, BiT);
  pair_softmax_kernel<<<ROWS / 2, 512, 0, stream>>>(Zj, Zi, Aj, BiT, W1, W2,
                                                    mask, probs);
  // ctx[b] = probs[b] @ Hi[b]   (M=512, N=1024, K=512, batched over b)
  gemm_kernel<false, false><<<dim3(16, 8, 2), 256, 0, stream>>>(
      probs, nullptr, Hi, nullptr, nullptr, ctx,
      512, HDIM, 512, 0, (long)512 * 512, 0, (long)512 * HDIM, (long)512 * HDIM);
  // hidden = relu([ctx | Hj] @ Wv1 + bv1)   (M=1024, N=1024, K=2048)
  gemm_kernel<true, false><<<dim3(16, 16, 1), 256, 0, stream>>>(
      ctx, Hj, Wv1, bv1, nullptr, hidden,
      ROWS, HDIM, HDIM, HDIM, 0, 0, 0, 0);
  // out = alpha * (hidden @ Wv2 + bv2)      (M=1024, N=1024, K=1024)
  gemm_kernel<false, true><<<dim3(16, 16, 1), 256, 0, stream>>>(
      hidden, nullptr, Wv2, bv2, alpha, out,
      ROWS, HDIM, HDIM, 0, 0, 0, 0, 0);
}

// Round 2
// 152.215 us; speedup vs baseline: 2.1181x; 2.1181x over previous
//
#include <hip/hip_runtime.h>
#include <hip/hip_bf16.h>
#include <math.h>

#define B_    2
#define S_    512
#define HDIM  1024
#define D_    24      // proj dim
#define M_    96      // pair-MLP hidden
#define ROWS  (B_*S_) // 1024

typedef __bf16 bf16x8 __attribute__((ext_vector_type(8)));
typedef float  f32x4  __attribute__((ext_vector_type(4)));

// ---------------------------------------------------------------------------
// K1: Zj = H_j @ p_j, Zi = H_i @ p_i   -> [ROWS][24]   (one wave per row)
// ---------------------------------------------------------------------------
__global__ __launch_bounds__(64) void proj_kernel(
    const float* __restrict__ Hj, const float* __restrict__ Hi,
    const float* __restrict__ pj, const float* __restrict__ pi,
    float* __restrict__ Zj, float* __restrict__ Zi) {
  int r = blockIdx.x;
  int lane = threadIdx.x;
  const float* hj = Hj + (size_t)r * HDIM;
  const float* hi = Hi + (size_t)r * HDIM;
  float accj[D_], acci[D_];
#pragma unroll
  for (int d = 0; d < D_; ++d) { accj[d] = 0.f; acci[d] = 0.f; }
  for (int k = lane; k < HDIM; k += 64) {
    float a = hj[k], b = hi[k];
    const float* pjr = pj + k * D_;
    const float* pir = pi + k * D_;
#pragma unroll
    for (int d = 0; d < D_; ++d) {
      accj[d] = fmaf(a, pjr[d], accj[d]);
      acci[d] = fmaf(b, pir[d], acci[d]);
    }
  }
#pragma unroll
  for (int d = 0; d < D_; ++d) {
    for (int off = 32; off > 0; off >>= 1) {
      accj[d] += __shfl_down(accj[d], off, 64);
      acci[d] += __shfl_down(acci[d], off, 64);
    }
  }
  if (lane == 0) {
#pragma unroll
    for (int d = 0; d < D_; ++d) {
      Zj[r * D_ + d] = accj[d];
      Zi[r * D_ + d] = acci[d];
    }
  }
}

// ---------------------------------------------------------------------------
// K2: Aj[r][m] = b1[m] + sum_d Zj[r][d]*W1[d][m]
//     BiT[m][r] =        sum_d Zi[r][d]*W1[24+d][m]   (transposed)
// ---------------------------------------------------------------------------
__global__ __launch_bounds__(128) void ab_kernel(
    const float* __restrict__ Zj, const float* __restrict__ Zi,
    const float* __restrict__ W1, const float* __restrict__ b1,
    float* __restrict__ Aj, float* __restrict__ BiT) {
  int r = blockIdx.x;
  int m = threadIdx.x;
  __shared__ float zj[D_], zi[D_];
  if (m < D_) { zj[m] = Zj[r * D_ + m]; zi[m] = Zi[r * D_ + m]; }
  __syncthreads();
  if (m < M_) {
    float aj = b1[m], bi = 0.f;
#pragma unroll
    for (int d = 0; d < D_; ++d) {
      aj = fmaf(zj[d], W1[d * M_ + m], aj);
      bi = fmaf(zi[d], W1[(D_ + d) * M_ + m], bi);
    }
    Aj[r * M_ + m] = aj;
    BiT[(size_t)m * ROWS + r] = bi;
  }
}

// ---------------------------------------------------------------------------
// K3: pair-MLP logits + masked softmax; writes probs as bf16 [B,S,S]
// ---------------------------------------------------------------------------
__global__ __launch_bounds__(512) void pair_softmax_kernel(
    const float* __restrict__ Zj, const float* __restrict__ Zi,
    const float* __restrict__ Aj, const float* __restrict__ BiT,
    const float* __restrict__ W1, const float* __restrict__ W2,
    const float* __restrict__ mask, __hip_bfloat16* __restrict__ probs) {
  __shared__ float Wct[M_ * D_];
  __shared__ float Wdt[M_ * D_];
  __shared__ float W2s[M_];
  __shared__ float zjL[2][D_];
  __shared__ float AjL[2][M_];
  __shared__ float logitsL[2][S_];
  __shared__ float red[16];

  int t = threadIdx.x;
  int bj = blockIdx.x;
  int b = bj >> 8;
  int j0 = (bj & 255) * 2;
  int rj0 = b * S_ + j0;

  for (int idx = t; idx < M_ * D_; idx += 512) {
    int m = idx / D_, d = idx - m * D_;
    Wct[idx] = W1[(2 * D_ + d) * M_ + m];
    Wdt[idx] = W1[(3 * D_ + d) * M_ + m];
  }
  if (t < M_) W2s[t] = W2[t];
  if (t < 2 * D_) zjL[t / D_][t % D_] = Zj[(rj0 + t / D_) * D_ + (t % D_)];
  if (t < 2 * M_) AjL[t / M_][t % M_] = Aj[(rj0 + t / M_) * M_ + (t % M_)];
  __syncthreads();

  int jj = t >> 8;
  int ii = t & 255;

  float zj[D_];
#pragma unroll
  for (int d = 0; d < D_; ++d) zj[d] = zjL[jj][d];

  for (int istep = 0; istep < 2; ++istep) {
    int i = istep * 256 + ii;
    const float* zir = Zi + (size_t)(b * S_ + i) * D_;
    float prod[D_], adiff[D_];
#pragma unroll
    for (int d = 0; d < D_; ++d) {
      float z = zir[d];
      prod[d] = zj[d] * z;
      adiff[d] = fabsf(zj[d] - z);
    }
    float acc = 0.f;
    const float* bit = BiT + (b * S_ + i);
#pragma unroll 2
    for (int m = 0; m < M_; ++m) {
      float h = AjL[jj][m] + bit[(size_t)m * ROWS];
      const float* wc = &Wct[m * D_];
      const float* wd = &Wdt[m * D_];
#pragma unroll
      for (int d = 0; d < D_; ++d) {
        h = fmaf(prod[d], wc[d], h);
        h = fmaf(adiff[d], wd[d], h);
      }
      acc = fmaf(fmaxf(h, 0.f), W2s[m], acc);
    }
    float lg = acc + (1.0f - mask[b * S_ + i]) * (-3.40282347e38f);
    logitsL[jj][i] = lg;
  }
  __syncthreads();

  int w = t >> 6, lane = t & 63;
  int row = w >> 2, q = w & 3;
  int i1 = q * 64 + lane;
  int i2 = i1 + 256;
  float l1 = logitsL[row][i1], l2 = logitsL[row][i2];
  float mx = fmaxf(l1, l2);
#pragma unroll
  for (int off = 32; off > 0; off >>= 1) mx = fmaxf(mx, __shfl_down(mx, off, 64));
  if (lane == 0) red[w] = mx;
  __syncthreads();
  float rmax = fmaxf(fmaxf(red[row * 4 + 0], red[row * 4 + 1]),
                     fmaxf(red[row * 4 + 2], red[row * 4 + 3]));
  float e1 = __expf(l1 - rmax);
  float e2 = __expf(l2 - rmax);
  float s = e1 + e2;
#pragma unroll
  for (int off = 32; off > 0; off >>= 1) s += __shfl_down(s, off, 64);
  if (lane == 0) red[8 + w] = s;
  __syncthreads();
  float rsum = red[8 + row * 4 + 0] + red[8 + row * 4 + 1] +
               red[8 + row * 4 + 2] + red[8 + row * 4 + 3];
  float inv = 1.0f / rsum;
  size_t base = (size_t)(rj0 + row) * S_;
  probs[base + i1] = __float2bfloat16(e1 * inv);
  probs[base + i2] = __float2bfloat16(e2 * inv);
}

// ---------------------------------------------------------------------------
// fp32 -> bf16 row-major convert (n4 = elems/4)
// ---------------------------------------------------------------------------
__global__ __launch_bounds__(256) void conv_bf16_kernel(
    const float* __restrict__ in, __hip_bfloat16* __restrict__ out) {
  int i = blockIdx.x * 256 + threadIdx.x;
  float4 v = ((const float4*)in)[i];
  __hip_bfloat16 o0 = __float2bfloat16(v.x);
  __hip_bfloat16 o1 = __float2bfloat16(v.y);
  __hip_bfloat16 o2 = __float2bfloat16(v.z);
  __hip_bfloat16 o3 = __float2bfloat16(v.w);
  ushort4 o = { *(unsigned short*)&o0, *(unsigned short*)&o1,
                *(unsigned short*)&o2, *(unsigned short*)&o3 };
  ((ushort4*)out)[i] = o;
}

// ---------------------------------------------------------------------------
// fp32 [R][C] -> bf16 [C][R] transpose-convert, batched via z
// ---------------------------------------------------------------------------
__global__ __launch_bounds__(256) void transpose_bf16_kernel(
    const float* __restrict__ in, __hip_bfloat16* __restrict__ out,
    int R, int C, long inB, long outB) {
  __shared__ float tile[32][33];
  int bx = blockIdx.x * 32;  // col0 (C-dim)
  int by = blockIdx.y * 32;  // row0 (R-dim)
  const float* ib = in + (size_t)blockIdx.z * inB;
  __hip_bfloat16* ob = out + (size_t)blockIdx.z * outB;
  int tx = threadIdx.x & 31, ty = threadIdx.x >> 5;
#pragma unroll
  for (int k = 0; k < 4; ++k)
    tile[ty + k * 8][tx] = ib[(size_t)(by + ty + k * 8) * C + bx + tx];
  __syncthreads();
#pragma unroll
  for (int k = 0; k < 4; ++k)
    ob[(size_t)(bx + ty + k * 8) * R + by + tx] =
        __float2bfloat16(tile[tx][ty + k * 8]);
}

// ---------------------------------------------------------------------------
// bf16 MFMA GEMM: C = epi( [A0|A1](MxK) @ Bt(NxK)^T + bias )
// 64x64 tile, BK=32, 256 thr (4 waves, one 32x32 quadrant each).
// global_load_lds staging (16B), source-swizzled chunks, 4-buffer ring,
// depth-3 prefetch with counted vmcnt.
// ---------------------------------------------------------------------------
template <bool HASA1, bool RELU, bool FINAL, bool OUTBF>
__global__ __launch_bounds__(256) void mfma_gemm_kernel(
    const __hip_bfloat16* __restrict__ A0, const __hip_bfloat16* __restrict__ A1,
    const __hip_bfloat16* __restrict__ Bt, const float* __restrict__ bias,
    const float* __restrict__ alpha_ptr, void* __restrict__ Cout,
    int M, int N, int K0, int K1,
    long aB0, long aB1, long bB, long cB) {
  __shared__ __attribute__((aligned(16))) char smem[4 * 8192];
  const int t = threadIdx.x;
  const int w = t >> 6, l = t & 63;
  const int K = K0 + K1;
  const int NT = K >> 5;
  const int n0 = blockIdx.x * 64, m0 = blockIdx.y * 64;
  const int zb = blockIdx.z;
  const __hip_bfloat16* A0b = A0 + (size_t)zb * aB0;
  const __hip_bfloat16* A1b = HASA1 ? (A1 + (size_t)zb * aB1) : nullptr;
  const __hip_bfloat16* Btb = Bt + (size_t)zb * bB;

  // staging geometry: thread t covers LDS bytes t*16..+16 of each 4KB tile.
  // tile row sr = t>>2, chunk c = t&3; fetch global chunk c ^ ((sr>>1)&3).
  const int sr = (w << 4) + (l >> 2);
  const int sk = ((l & 3) ^ ((l >> 3) & 3)) << 3;  // element offset in k

  // fragment LDS byte offsets (within one 8KB buffer), swizzle-matched
  const int mq = w >> 1, nq = w & 1;
  int offA[2], offB[2];
#pragma unroll
  for (int i = 0; i < 2; ++i) {
    int ra = mq * 32 + i * 16 + (l & 15);
    offA[i] = ra * 64 + (((l >> 4) ^ ((ra >> 1) & 3)) << 4);
    int rb = nq * 32 + i * 16 + (l & 15);
    offB[i] = 4096 + rb * 64 + (((l >> 4) ^ ((rb >> 1) & 3)) << 4);
  }

  f32x4 acc[2][2] = {};

  auto stage = [&](int tt) {
    char* buf = smem + (tt & 3) * 8192;
    int ka = (tt << 5) + sk;
    const __hip_bfloat16* ga;
    if (HASA1 && ka >= K0) ga = A1b + (size_t)(m0 + sr) * K1 + (ka - K0);
    else                   ga = A0b + (size_t)(m0 + sr) * K0 + ka;
    __builtin_amdgcn_global_load_lds(
        (const __attribute__((address_space(1))) void*)ga,
        (__attribute__((address_space(3))) void*)(buf + (w << 10)), 16, 0, 0);
    const __hip_bfloat16* gb = Btb + (size_t)(n0 + sr) * K + ka;
    __builtin_amdgcn_global_load_lds(
        (const __attribute__((address_space(1))) void*)gb,
        (__attribute__((address_space(3))) void*)(buf + 4096 + (w << 10)), 16, 0, 0);
  };

  stage(0);
  if (NT > 1) stage(1);
  if (NT > 2) stage(2);

  for (int tt = 0; tt < NT; ++tt) {
    if (tt + 2 < NT)      asm volatile("s_waitcnt vmcnt(4)" ::: "memory");
    else if (tt + 1 < NT) asm volatile("s_waitcnt vmcnt(2)" ::: "memory");
    else                  asm volatile("s_waitcnt vmcnt(0)" ::: "memory");
    __builtin_amdgcn_s_barrier();
    __builtin_amdgcn_sched_barrier(0);
    const char* buf = smem + (tt & 3) * 8192;
    bf16x8 a0 = *(const bf16x8*)(buf + offA[0]);
    bf16x8 a1 = *(const bf16x8*)(buf + offA[1]);
    bf16x8 b0 = *(const bf16x8*)(buf + offB[0]);
    bf16x8 b1 = *(const bf16x8*)(buf + offB[1]);
    acc[0][0] = __builtin_amdgcn_mfma_f32_16x16x32_bf16(a0, b0, acc[0][0], 0, 0, 0);
    acc[0][1] = __builtin_amdgcn_mfma_f32_16x16x32_bf16(a0, b1, acc[0][1], 0, 0, 0);
    acc[1][0] = __builtin_amdgcn_mfma_f32_16x16x32_bf16(a1, b0, acc[1][0], 0, 0, 0);
    acc[1][1] = __builtin_amdgcn_mfma_f32_16x16x32_bf16(a1, b1, acc[1][1], 0, 0, 0);
    if (tt + 3 < NT) stage(tt + 3);
  }

  const float alpha = FINAL ? *alpha_ptr : 1.0f;
  const int lr = l & 15, lq = l >> 4;
  const size_t cbase = (size_t)zb * cB;
#pragma unroll
  for (int mi = 0; mi < 2; ++mi)
#pragma unroll
    for (int ni = 0; ni < 2; ++ni) {
      int col = n0 + nq * 32 + ni * 16 + lr;
      float bv = bias ? bias[col] : 0.0f;
#pragma unroll
      for (int rg = 0; rg < 4; ++rg) {
        int row = m0 + mq * 32 + mi * 16 + lq * 4 + rg;
        float x = acc[mi][ni][rg] + bv;
        if (RELU) x = fmaxf(x, 0.f);
        if (FINAL) x *= alpha;
        if (OUTBF)
          ((__hip_bfloat16*)Cout)[cbase + (size_t)row * N + col] = __float2bfloat16(x);
        else
          ((float*)Cout)[cbase + (size_t)row * N + col] = x;
      }
    }
}

// ---------------------------------------------------------------------------
extern "C" void kernel_launch(void* const* d_in, const int* in_sizes, int n_in,
                              void* d_out, int out_size, void* d_ws, size_t ws_size,
                              hipStream_t stream) {
  const float* Hj   = (const float*)d_in[0];
  const float* Hi   = (const float*)d_in[1];
  const float* mask = (const float*)d_in[2];
  const float* pj   = (const float*)d_in[3];
  const float* pi   = (const float*)d_in[4];
  const float* W1   = (const float*)d_in[5];
  const float* b1   = (const float*)d_in[6];
  const float* W2   = (const float*)d_in[7];
  // d_in[8] = b2: uniform over keys -> softmax invariant, unused
  const float* Wv1  = (const float*)d_in[9];
  const float* bv1  = (const float*)d_in[10];
  const float* Wv2  = (const float*)d_in[11];
  const float* bv2  = (const float*)d_in[12];
  const float* alpha = (const float*)d_in[13];

  char* w = (char*)d_ws;
  float* Zj  = (float*)w;            w += (size_t)ROWS * D_ * 4;
  float* Zi  = (float*)w;            w += (size_t)ROWS * D_ * 4;
  float* Aj  = (float*)w;            w += (size_t)ROWS * M_ * 4;
  float* BiT = (float*)w;            w += (size_t)M_ * ROWS * 4;
  __hip_bfloat16* probsB = (__hip_bfloat16*)w; w += (size_t)B_ * S_ * S_ * 2;
  __hip_bfloat16* HjB    = (__hip_bfloat16*)w; w += (size_t)ROWS * HDIM * 2;
  __hip_bfloat16* HiT    = (__hip_bfloat16*)w; w += (size_t)B_ * HDIM * S_ * 2;
  __hip_bfloat16* Wv1T   = (__hip_bfloat16*)w; w += (size_t)HDIM * 2 * HDIM * 2;
  __hip_bfloat16* Wv2T   = (__hip_bfloat16*)w; w += (size_t)HDIM * HDIM * 2;
  __hip_bfloat16* ctxB   = (__hip_bfloat16*)w; w += (size_t)ROWS * HDIM * 2;
  __hip_bfloat16* hidB   = (__hip_bfloat16*)w; w += (size_t)ROWS * HDIM * 2;
  float* out = (float*)d_out;

  // dtype prep
  conv_bf16_kernel<<<ROWS * HDIM / 4 / 256, 256, 0, stream>>>(Hj, HjB);
  transpose_bf16_kernel<<<dim3(HDIM / 32, S_ / 32, B_), 256, 0, stream>>>(
      Hi, HiT, S_, HDIM, (long)S_ * HDIM, (long)HDIM * S_);
  transpose_bf16_kernel<<<dim3(HDIM / 32, 2 * HDIM / 32, 1), 256, 0, stream>>>(
      Wv1, Wv1T, 2 * HDIM, HDIM, 0, 0);
  transpose_bf16_kernel<<<dim3(HDIM / 32, HDIM / 32, 1), 256, 0, stream>>>(
      Wv2, Wv2T, HDIM, HDIM, 0, 0);

  // scoring path
  proj_kernel<<<ROWS, 64, 0, stream>>>(Hj, Hi, pj, pi, Zj, Zi);
  ab_kernel<<<ROWS, 128, 0, stream>>>(Zj, Zi, W1, b1, Aj, BiT);
  pair_softmax_kernel<<<ROWS / 2, 512, 0, stream>>>(Zj, Zi, Aj, BiT, W1, W2,
                                                    mask, probsB);

  // ctx[b] = probs[b] @ Hi[b]   (M=512, N=1024, K=512) -> bf16
  mfma_gemm_kernel<false, false, false, true><<<dim3(16, 8, 2), 256, 0, stream>>>(
      probsB, nullptr, HiT, nullptr, nullptr, ctxB,
      S_, HDIM, S_, 0, (long)S_ * S_, 0, (long)HDIM * S_, (long)S_ * HDIM);
  // hidden = relu([ctx | Hj] @ Wv1 + bv1)   (M=1024, N=1024, K=2048) -> bf16
  mfma_gemm_kernel<true, true, false, true><<<dim3(16, 16, 1), 256, 0, stream>>>(
      ctxB, HjB, Wv1T, bv1, nullptr, hidB,
      ROWS, HDIM, HDIM, HDIM, 0, 0, 0, 0);
  // out = alpha * (hidden @ Wv2 + bv2)      (M=1024, N=1024, K=1024) -> fp32
  mfma_gemm_kernel<false, false, true, false><<<dim3(16, 16, 1), 256, 0, stream>>>(
      hidB, nullptr, Wv2T, bv2, alpha, out,
      ROWS, HDIM, HDIM, 0, 0, 0, 0, 0);
}

// Round 3
// 87.145 us; speedup vs baseline: 3.6997x; 1.7467x over previous
//
#include <hip/hip_runtime.h>
#include <math.h>

#define B_    2
#define S_    512
#define HDIM  1024
#define D_    24      // proj dim
#define M_    96      // pair-MLP hidden
#define ROWS  (B_*S_) // 1024

typedef _Float16 half8 __attribute__((ext_vector_type(8)));
typedef float    f32x4 __attribute__((ext_vector_type(4)));

// ---------------------------------------------------------------------------
// K1: Zj = H_j @ p_j, Zi = H_i @ p_i   -> [ROWS][24]   (one wave per row)
// ---------------------------------------------------------------------------
__global__ __launch_bounds__(64) void proj_kernel(
    const float* __restrict__ Hj, const float* __restrict__ Hi,
    const float* __restrict__ pj, const float* __restrict__ pi,
    float* __restrict__ Zj, float* __restrict__ Zi) {
  int r = blockIdx.x;
  int lane = threadIdx.x;
  const float* hj = Hj + (size_t)r * HDIM;
  const float* hi = Hi + (size_t)r * HDIM;
  float accj[D_], acci[D_];
#pragma unroll
  for (int d = 0; d < D_; ++d) { accj[d] = 0.f; acci[d] = 0.f; }
  for (int k = lane; k < HDIM; k += 64) {
    float a = hj[k], b = hi[k];
    const float* pjr = pj + k * D_;
    const float* pir = pi + k * D_;
#pragma unroll
    for (int d = 0; d < D_; ++d) {
      accj[d] = fmaf(a, pjr[d], accj[d]);
      acci[d] = fmaf(b, pir[d], acci[d]);
    }
  }
#pragma unroll
  for (int d = 0; d < D_; ++d) {
    for (int off = 32; off > 0; off >>= 1) {
      accj[d] += __shfl_down(accj[d], off, 64);
      acci[d] += __shfl_down(acci[d], off, 64);
    }
  }
  if (lane == 0) {
#pragma unroll
    for (int d = 0; d < D_; ++d) {
      Zj[r * D_ + d] = accj[d];
      Zi[r * D_ + d] = acci[d];
    }
  }
}

// ---------------------------------------------------------------------------
// prep: Wimg = fp16 image of W1 rows 24..95 in k-chunk-subtiled LDS layout.
// chunk c (< 864): kc=c/96, m=c%96, elems e -> W1[(24+kc*8+e)][m].
// chunks 864..1023: zeros (Aj row slot + zero chunk + pad).
// ---------------------------------------------------------------------------
__global__ __launch_bounds__(256) void prep_w_kernel(
    const float* __restrict__ W1, _Float16* __restrict__ Wimg) {
  int c = blockIdx.x * 256 + threadIdx.x;   // 0..1023
  half8 v = {};
  if (c < 864) {
    int kc = c / 96, m = c - kc * 96;
#pragma unroll
    for (int e = 0; e < 8; ++e)
      v[e] = (_Float16)W1[(24 + kc * 8 + e) * M_ + m];
  }
  *(half8*)(Wimg + (size_t)c * 8) = v;
}

// ---------------------------------------------------------------------------
// Fused pair-MLP + softmax. One block per j-row (1024 blocks, 256 thr).
// logits[j][i] = relu(F_j[i] @ Wbig) . W2 ; masked softmax; probs fp16.
// F_j[i] (K=80, padded 96) = [Zi | Zj*Zi | |Zj-Zi| | 1 | 0...]
// Wbig = [W1[24:96] ; Aj_row ; 0...]  (Aj_row = b1 + Zj@W1[0:24])
// MFMA 16x16x32 f16: M=i, N=m.
// ---------------------------------------------------------------------------
#define FOFFB   0                       // 10*256*16 = 40960
#define WOFFB   40960                   // 1024 chunks * 16 = 16384
#define ZOFFB   (WOFFB + 960*16)        // zero chunk (staged zero)
#define LOGOFFB (WOFFB + 16384)         // 512 f32 logits
#define ZJOFFB  (LOGOFFB + 2048)        // 24 f32
#define W2OFFB  (ZJOFFB + 96)           // 96 f32
#define REDOFFB (W2OFFB + 384)          // 8 f32
#define LDSB    (REDOFFB + 32)          // 59936

__global__ __launch_bounds__(256) void pair_fused_kernel(
    const float* __restrict__ Zj, const float* __restrict__ Zi,
    const float* __restrict__ W1, const float* __restrict__ b1,
    const float* __restrict__ W2, const _Float16* __restrict__ Wimg,
    const float* __restrict__ mask, _Float16* __restrict__ probs) {
  __shared__ __attribute__((aligned(16))) char smem[LDSB];
  const int t = threadIdx.x;
  const int w = t >> 6, l = t & 63;
  const int lo = l & 15, hi = l >> 4;
  const int rj = blockIdx.x;         // global row j (b*512+j)
  const int b = rj >> 9;

  // stage weight image (1024 chunks incl. zero pad) -> LDS, wave-linear
#pragma unroll
  for (int r = 0; r < 4; ++r) {
    const _Float16* src = Wimg + (size_t)(r * 256 + w * 64 + l) * 8;
    __builtin_amdgcn_global_load_lds(
        (const __attribute__((address_space(1))) void*)src,
        (__attribute__((address_space(3))) void*)(smem + WOFFB + (r * 256 + w * 64) * 16),
        16, 0, 0);
  }
  float* zjL    = (float*)(smem + ZJOFFB);
  float* W2s    = (float*)(smem + W2OFFB);
  float* logits = (float*)(smem + LOGOFFB);
  float* red    = (float*)(smem + REDOFFB);
  if (t < D_) zjL[t] = Zj[(size_t)rj * D_ + t];
  if (t < M_) W2s[t] = W2[t];
  // Aj row (weight row k=72) into regs while staging flies
  float aj = 0.f;
  if (t < M_) {
    aj = b1[t];
#pragma unroll
    for (int d = 0; d < D_; ++d)
      aj = fmaf(Zj[(size_t)rj * D_ + d], W1[d * M_ + t], aj);
  }
  __syncthreads();   // staging + zjL/W2s visible
  if (t < M_) {
    half8 v = {};
    v[0] = (_Float16)aj;
    *(half8*)(smem + WOFFB + (864 + t) * 16) = v;
  }
  float zjv[D_];
#pragma unroll
  for (int d = 0; d < D_; ++d) zjv[d] = zjL[d];

  for (int p = 0; p < 2; ++p) {
    // ---- feature build: this thread owns key i = p*256 + t ----
    {
      int i = p * 256 + t;
      const float* zi = Zi + (size_t)(b * S_ + i) * D_;
      float ziv[D_];
#pragma unroll
      for (int d = 0; d < D_; ++d) ziv[d] = zi[d];
#pragma unroll
      for (int kc = 0; kc < 3; ++kc) {
        half8 v;
#pragma unroll
        for (int e = 0; e < 8; ++e) v[e] = (_Float16)ziv[kc * 8 + e];
        *(half8*)(smem + FOFFB + (kc * 256 + t) * 16) = v;
      }
#pragma unroll
      for (int kc = 0; kc < 3; ++kc) {
        half8 v;
#pragma unroll
        for (int e = 0; e < 8; ++e) {
          int d = kc * 8 + e;
          v[e] = (_Float16)(zjv[d] * ziv[d]);
        }
        *(half8*)(smem + FOFFB + ((kc + 3) * 256 + t) * 16) = v;
      }
#pragma unroll
      for (int kc = 0; kc < 3; ++kc) {
        half8 v;
#pragma unroll
        for (int e = 0; e < 8; ++e) {
          int d = kc * 8 + e;
          v[e] = (_Float16)fabsf(zjv[d] - ziv[d]);
        }
        *(half8*)(smem + FOFFB + ((kc + 6) * 256 + t) * 16) = v;
      }
      if (p == 0) {
        half8 v = {};
        v[0] = (_Float16)1.0f;
        *(half8*)(smem + FOFFB + (9 * 256 + t) * 16) = v;
      }
    }
    __syncthreads();

    // ---- MFMA: wave w owns i_local = w*64 .. w*64+63 (4 M-tiles) ----
    half8 af[4][3];
#pragma unroll
    for (int mt = 0; mt < 4; ++mt)
#pragma unroll
      for (int ks = 0; ks < 3; ++ks) {
        int kc = ks * 4 + hi;
        int off = (kc < 10) ? (FOFFB + (kc * 256 + w * 64 + mt * 16 + lo) * 16) : ZOFFB;
        af[mt][ks] = *(const half8*)(smem + off);
      }
    f32x4 plog[4] = {};
    for (int nc = 0; nc < 6; ++nc) {
      half8 bf[3];
#pragma unroll
      for (int ks = 0; ks < 3; ++ks) {
        int kc = ks * 4 + hi;
        int off = (kc < 10) ? (WOFFB + (kc * 96 + nc * 16 + lo) * 16) : ZOFFB;
        bf[ks] = *(const half8*)(smem + off);
      }
      f32x4 acc[4] = {};
#pragma unroll
      for (int ks = 0; ks < 3; ++ks)
#pragma unroll
        for (int mt = 0; mt < 4; ++mt)
          acc[mt] = __builtin_amdgcn_mfma_f32_16x16x32_f16(af[mt][ks], bf[ks], acc[mt], 0, 0, 0);
      float w2v = W2s[nc * 16 + lo];
#pragma unroll
      for (int mt = 0; mt < 4; ++mt)
#pragma unroll
        for (int r = 0; r < 4; ++r)
          plog[mt][r] = fmaf(fmaxf(acc[mt][r], 0.f), w2v, plog[mt][r]);
    }
    // sum over the 16 m-columns held across each 16-lane group
#pragma unroll
    for (int mt = 0; mt < 4; ++mt)
#pragma unroll
      for (int r = 0; r < 4; ++r) {
        float v = plog[mt][r];
        v += __shfl_xor(v, 1);
        v += __shfl_xor(v, 2);
        v += __shfl_xor(v, 4);
        v += __shfl_xor(v, 8);
        plog[mt][r] = v;
      }
    if (lo == 0) {
#pragma unroll
      for (int mt = 0; mt < 4; ++mt)
#pragma unroll
        for (int r = 0; r < 4; ++r)
          logits[p * 256 + w * 64 + mt * 16 + hi * 4 + r] = plog[mt][r];
    }
    __syncthreads();
  }

  // ---- masked softmax over 512 keys (b2 dropped: shift-invariant) ----
  float m1 = mask[b * S_ + t], m2 = mask[b * S_ + t + 256];
  float lg1 = logits[t]       + (1.0f - m1) * (-3.40282347e38f);
  float lg2 = logits[t + 256] + (1.0f - m2) * (-3.40282347e38f);
  float mx = fmaxf(lg1, lg2);
#pragma unroll
  for (int off = 32; off > 0; off >>= 1) mx = fmaxf(mx, __shfl_xor(mx, off));
  if (l == 0) red[w] = mx;
  __syncthreads();
  float rmax = fmaxf(fmaxf(red[0], red[1]), fmaxf(red[2], red[3]));
  float e1 = __expf(lg1 - rmax);
  float e2 = __expf(lg2 - rmax);
  float s = e1 + e2;
#pragma unroll
  for (int off = 32; off > 0; off >>= 1) s += __shfl_xor(s, off);
  if (l == 0) red[4 + w] = s;
  __syncthreads();
  float inv = 1.0f / (red[4] + red[5] + red[6] + red[7]);
  probs[(size_t)rj * S_ + t]       = (_Float16)(e1 * inv);
  probs[(size_t)rj * S_ + t + 256] = (_Float16)(e2 * inv);
}

// ---------------------------------------------------------------------------
// fp32 -> fp16 row-major convert
// ---------------------------------------------------------------------------
__global__ __launch_bounds__(256) void conv_f16_kernel(
    const float* __restrict__ in, _Float16* __restrict__ out) {
  int i = blockIdx.x * 256 + threadIdx.x;
  float4 v = ((const float4*)in)[i];
  _Float16 o[4] = {(_Float16)v.x, (_Float16)v.y, (_Float16)v.z, (_Float16)v.w};
  ((ushort4*)out)[i] = *(ushort4*)o;
}

// ---------------------------------------------------------------------------
// fp32 [R][C] -> fp16 [C][R] transpose-convert, batched via z
// ---------------------------------------------------------------------------
__global__ __launch_bounds__(256) void transpose_f16_kernel(
    const float* __restrict__ in, _Float16* __restrict__ out,
    int R, int C, long inB, long outB) {
  __shared__ float tile[32][33];
  int bx = blockIdx.x * 32;
  int by = blockIdx.y * 32;
  const float* ib = in + (size_t)blockIdx.z * inB;
  _Float16* ob = out + (size_t)blockIdx.z * outB;
  int tx = threadIdx.x & 31, ty = threadIdx.x >> 5;
#pragma unroll
  for (int k = 0; k < 4; ++k)
    tile[ty + k * 8][tx] = ib[(size_t)(by + ty + k * 8) * C + bx + tx];
  __syncthreads();
#pragma unroll
  for (int k = 0; k < 4; ++k)
    ob[(size_t)(bx + ty + k * 8) * R + by + tx] = (_Float16)tile[tx][ty + k * 8];
}

// ---------------------------------------------------------------------------
// fp16 MFMA GEMM: C = epi( [A0|A1](MxK) @ Bt(NxK)^T + bias )
// 64x64 tile, BK=32, 4 waves (one 32x32 quadrant each), global_load_lds
// staging with source swizzle, 4-buffer ring, depth-3 prefetch, counted vmcnt.
// ---------------------------------------------------------------------------
template <bool HASA1, bool RELU, bool FINAL, bool OUTH>
__global__ __launch_bounds__(256) void mfma_gemm_kernel(
    const _Float16* __restrict__ A0, const _Float16* __restrict__ A1,
    const _Float16* __restrict__ Bt, const float* __restrict__ bias,
    const float* __restrict__ alpha_ptr, void* __restrict__ Cout,
    int M, int N, int K0, int K1,
    long aB0, long aB1, long bB, long cB) {
  __shared__ __attribute__((aligned(16))) char smem[4 * 8192];
  const int t = threadIdx.x;
  const int w = t >> 6, l = t & 63;
  const int K = K0 + K1;
  const int NT = K >> 5;
  const int n0 = blockIdx.x * 64, m0 = blockIdx.y * 64;
  const int zb = blockIdx.z;
  const _Float16* A0b = A0 + (size_t)zb * aB0;
  const _Float16* A1b = HASA1 ? (A1 + (size_t)zb * aB1) : nullptr;
  const _Float16* Btb = Bt + (size_t)zb * bB;

  const int sr = (w << 4) + (l >> 2);
  const int sk = ((l & 3) ^ ((l >> 3) & 3)) << 3;

  const int mq = w >> 1, nq = w & 1;
  int offA[2], offB[2];
#pragma unroll
  for (int i = 0; i < 2; ++i) {
    int ra = mq * 32 + i * 16 + (l & 15);
    offA[i] = ra * 64 + (((l >> 4) ^ ((ra >> 1) & 3)) << 4);
    int rb = nq * 32 + i * 16 + (l & 15);
    offB[i] = 4096 + rb * 64 + (((l >> 4) ^ ((rb >> 1) & 3)) << 4);
  }

  f32x4 acc[2][2] = {};

  auto stage = [&](int tt) {
    char* buf = smem + (tt & 3) * 8192;
    int ka = (tt << 5) + sk;
    const _Float16* ga;
    if (HASA1 && ka >= K0) ga = A1b + (size_t)(m0 + sr) * K1 + (ka - K0);
    else                   ga = A0b + (size_t)(m0 + sr) * K0 + ka;
    __builtin_amdgcn_global_load_lds(
        (const __attribute__((address_space(1))) void*)ga,
        (__attribute__((address_space(3))) void*)(buf + (w << 10)), 16, 0, 0);
    const _Float16* gb = Btb + (size_t)(n0 + sr) * K + ka;
    __builtin_amdgcn_global_load_lds(
        (const __attribute__((address_space(1))) void*)gb,
        (__attribute__((address_space(3))) void*)(buf + 4096 + (w << 10)), 16, 0, 0);
  };

  stage(0);
  if (NT > 1) stage(1);
  if (NT > 2) stage(2);

  for (int tt = 0; tt < NT; ++tt) {
    if (tt + 2 < NT)      asm volatile("s_waitcnt vmcnt(4)" ::: "memory");
    else if (tt + 1 < NT) asm volatile("s_waitcnt vmcnt(2)" ::: "memory");
    else                  asm volatile("s_waitcnt vmcnt(0)" ::: "memory");
    __builtin_amdgcn_s_barrier();
    __builtin_amdgcn_sched_barrier(0);
    const char* buf = smem + (tt & 3) * 8192;
    half8 a0 = *(const half8*)(buf + offA[0]);
    half8 a1 = *(const half8*)(buf + offA[1]);
    half8 b0 = *(const half8*)(buf + offB[0]);
    half8 b1v = *(const half8*)(buf + offB[1]);
    acc[0][0] = __builtin_amdgcn_mfma_f32_16x16x32_f16(a0, b0, acc[0][0], 0, 0, 0);
    acc[0][1] = __builtin_amdgcn_mfma_f32_16x16x32_f16(a0, b1v, acc[0][1], 0, 0, 0);
    acc[1][0] = __builtin_amdgcn_mfma_f32_16x16x32_f16(a1, b0, acc[1][0], 0, 0, 0);
    acc[1][1] = __builtin_amdgcn_mfma_f32_16x16x32_f16(a1, b1v, acc[1][1], 0, 0, 0);
    if (tt + 3 < NT) stage(tt + 3);
  }

  const float alpha = FINAL ? *alpha_ptr : 1.0f;
  const int lr = l & 15, lq = l >> 4;
  const size_t cbase = (size_t)zb * cB;
#pragma unroll
  for (int mi = 0; mi < 2; ++mi)
#pragma unroll
    for (int ni = 0; ni < 2; ++ni) {
      int col = n0 + nq * 32 + ni * 16 + lr;
      float bv = bias ? bias[col] : 0.0f;
#pragma unroll
      for (int rg = 0; rg < 4; ++rg) {
        int row = m0 + mq * 32 + mi * 16 + lq * 4 + rg;
        float x = acc[mi][ni][rg] + bv;
        if (RELU) x = fmaxf(x, 0.f);
        if (FINAL) x *= alpha;
        if (OUTH)
          ((_Float16*)Cout)[cbase + (size_t)row * N + col] = (_Float16)x;
        else
          ((float*)Cout)[cbase + (size_t)row * N + col] = x;
      }
    }
}

// ---------------------------------------------------------------------------
extern "C" void kernel_launch(void* const* d_in, const int* in_sizes, int n_in,
                              void* d_out, int out_size, void* d_ws, size_t ws_size,
                              hipStream_t stream) {
  const float* Hj   = (const float*)d_in[0];
  const float* Hi   = (const float*)d_in[1];
  const float* mask = (const float*)d_in[2];
  const float* pj   = (const float*)d_in[3];
  const float* pi   = (const float*)d_in[4];
  const float* W1   = (const float*)d_in[5];
  const float* b1   = (const float*)d_in[6];
  const float* W2   = (const float*)d_in[7];
  // d_in[8] = b2: uniform over keys -> softmax invariant, unused
  const float* Wv1  = (const float*)d_in[9];
  const float* bv1  = (const float*)d_in[10];
  const float* Wv2  = (const float*)d_in[11];
  const float* bv2  = (const float*)d_in[12];
  const float* alpha = (const float*)d_in[13];

  char* w = (char*)d_ws;
  float* Zj  = (float*)w;            w += (size_t)ROWS * D_ * 4;
  float* Zi  = (float*)w;            w += (size_t)ROWS * D_ * 4;
  _Float16* Wimg   = (_Float16*)w;   w += (size_t)1024 * 16;
  _Float16* probsH = (_Float16*)w;   w += (size_t)B_ * S_ * S_ * 2;
  _Float16* HjH    = (_Float16*)w;   w += (size_t)ROWS * HDIM * 2;
  _Float16* HiT    = (_Float16*)w;   w += (size_t)B_ * HDIM * S_ * 2;
  _Float16* Wv1T   = (_Float16*)w;   w += (size_t)HDIM * 2 * HDIM * 2;
  _Float16* Wv2T   = (_Float16*)w;   w += (size_t)HDIM * HDIM * 2;
  _Float16* ctxH   = (_Float16*)w;   w += (size_t)ROWS * HDIM * 2;
  _Float16* hidH   = (_Float16*)w;   w += (size_t)ROWS * HDIM * 2;
  float* out = (float*)d_out;

  // dtype prep
  prep_w_kernel<<<4, 256, 0, stream>>>(W1, Wimg);
  conv_f16_kernel<<<ROWS * HDIM / 4 / 256, 256, 0, stream>>>(Hj, HjH);
  transpose_f16_kernel<<<dim3(HDIM / 32, S_ / 32, B_), 256, 0, stream>>>(
      Hi, HiT, S_, HDIM, (long)S_ * HDIM, (long)HDIM * S_);
  transpose_f16_kernel<<<dim3(HDIM / 32, 2 * HDIM / 32, 1), 256, 0, stream>>>(
      Wv1, Wv1T, 2 * HDIM, HDIM, 0, 0);
  transpose_f16_kernel<<<dim3(HDIM / 32, HDIM / 32, 1), 256, 0, stream>>>(
      Wv2, Wv2T, HDIM, HDIM, 0, 0);

  // scoring path
  proj_kernel<<<ROWS, 64, 0, stream>>>(Hj, Hi, pj, pi, Zj, Zi);
  pair_fused_kernel<<<ROWS, 256, 0, stream>>>(Zj, Zi, W1, b1, W2, Wimg,
                                              mask, probsH);

  // ctx[b] = probs[b] @ Hi[b]   (M=512, N=1024, K=512) -> fp16
  mfma_gemm_kernel<false, false, false, true><<<dim3(16, 8, 2), 256, 0, stream>>>(
      probsH, nullptr, HiT, nullptr, nullptr, ctxH,
      S_, HDIM, S_, 0, (long)S_ * S_, 0, (long)HDIM * S_, (long)S_ * HDIM);
  // hidden = relu([ctx | Hj] @ Wv1 + bv1)   (M=1024, N=1024, K=2048) -> fp16
  mfma_gemm_kernel<true, true, false, true><<<dim3(16, 16, 1), 256, 0, stream>>>(
      ctxH, HjH, Wv1T, bv1, nullptr, hidH,
      ROWS, HDIM, HDIM, HDIM, 0, 0, 0, 0);
  // out = alpha * (hidden @ Wv2 + bv2)      (M=1024, N=1024, K=1024) -> fp32
  mfma_gemm_kernel<false, false, true, false><<<dim3(16, 16, 1), 256, 0, stream>>>(
      hidH, nullptr, Wv2T, bv2, alpha, out,
      ROWS, HDIM, HDIM, 0, 0, 0, 0, 0);
}

// Round 4
// 76.224 us; speedup vs baseline: 4.2297x; 1.1433x over previous
//
#include <hip/hip_runtime.h>
#include <math.h>

#define B_    2
#define S_    512
#define HDIM  1024
#define D_    24      // proj dim
#define M_    96      // pair-MLP hidden
#define ROWS  (B_*S_) // 1024

typedef _Float16 half8 __attribute__((ext_vector_type(8)));
typedef float    f32x4 __attribute__((ext_vector_type(4)));

// ---------------------------------------------------------------------------
// transpose helper: fp32 [R][C] tile (xt,yt) -> fp16 out[C][R]
// ---------------------------------------------------------------------------
__device__ __forceinline__ void transpose_tile(
    const float* __restrict__ in, _Float16* __restrict__ out,
    int R, int C, int xt, int yt, float (*tile)[33], int t) {
  int bx = xt * 32, by = yt * 32;
  int tx = t & 31, ty = t >> 5;
#pragma unroll
  for (int k = 0; k < 4; ++k)
    tile[ty + k * 8][tx] = in[(size_t)(by + ty + k * 8) * C + bx + tx];
  __syncthreads();
#pragma unroll
  for (int k = 0; k < 4; ++k)
    out[(size_t)(bx + ty + k * 8) * R + by + tx] = (_Float16)tile[tx][ty + k * 8];
}

// ---------------------------------------------------------------------------
// Merged prep kernel: blockIdx ranges
//  [0,4)        : Wimg (fp16 subtiled image of W1 rows 24..95 + zero pad)
//  [4,1028)     : HjH = fp16(Hj)
//  [1028,2052)  : HiT = fp16 transpose of Hi (per batch)
//  [2052,4100)  : Wv1T
//  [4100,5124)  : Wv2T
//  [5124,5380)  : proj -> Zj, Zi  (4 rows per block, one wave each)
// ---------------------------------------------------------------------------
__global__ __launch_bounds__(256) void prep_kernel(
    const float* __restrict__ Hj, const float* __restrict__ Hi,
    const float* __restrict__ pj, const float* __restrict__ pi,
    const float* __restrict__ W1, const float* __restrict__ Wv1,
    const float* __restrict__ Wv2,
    _Float16* __restrict__ HjH, _Float16* __restrict__ HiT,
    _Float16* __restrict__ Wv1T, _Float16* __restrict__ Wv2T,
    _Float16* __restrict__ Wimg, float* __restrict__ Zj,
    float* __restrict__ Zi) {
  __shared__ float tile[32][33];
  const int bid = blockIdx.x;
  const int t = threadIdx.x;

  if (bid < 4) {
    int c = bid * 256 + t;   // 0..1023
    half8 v = {};
    if (c < 864) {
      int kc = c / 96, m = c - kc * 96;
#pragma unroll
      for (int e = 0; e < 8; ++e)
        v[e] = (_Float16)W1[(24 + kc * 8 + e) * M_ + m];
    }
    *(half8*)(Wimg + (size_t)c * 8) = v;
  } else if (bid < 1028) {
    int i = (bid - 4) * 256 + t;
    float4 v = ((const float4*)Hj)[i];
    _Float16 o[4] = {(_Float16)v.x, (_Float16)v.y, (_Float16)v.z, (_Float16)v.w};
    ((ushort4*)HjH)[i] = *(ushort4*)o;
  } else if (bid < 2052) {
    int id = bid - 1028;
    int z = id >> 9, rem = id & 511;
    transpose_tile(Hi + (size_t)z * S_ * HDIM, HiT + (size_t)z * HDIM * S_,
                   S_, HDIM, rem & 31, rem >> 5, tile, t);
  } else if (bid < 4100) {
    int id = bid - 2052;
    transpose_tile(Wv1, Wv1T, 2 * HDIM, HDIM, id & 31, id >> 5, tile, t);
  } else if (bid < 5124) {
    int id = bid - 4100;
    transpose_tile(Wv2, Wv2T, HDIM, HDIM, id & 31, id >> 5, tile, t);
  } else {
    int r = (bid - 5124) * 4 + (t >> 6);
    int lane = t & 63;
    float4 a4 = ((const float4*)(Hj + (size_t)r * HDIM))[lane];
    float4 c4 = ((const float4*)(Hi + (size_t)r * HDIM))[lane];
    float accj[D_], acci[D_];
#pragma unroll
    for (int d = 0; d < D_; ++d) { accj[d] = 0.f; acci[d] = 0.f; }
    const float* aa = (const float*)&a4;
    const float* cc = (const float*)&c4;
#pragma unroll
    for (int kk = 0; kk < 4; ++kk) {
      const float4* pj4 = (const float4*)(pj + (size_t)(lane * 4 + kk) * D_);
      const float4* pi4 = (const float4*)(pi + (size_t)(lane * 4 + kk) * D_);
      float a = aa[kk], c = cc[kk];
#pragma unroll
      for (int q = 0; q < 6; ++q) {
        float4 wj = pj4[q], wi = pi4[q];
        accj[q * 4 + 0] = fmaf(a, wj.x, accj[q * 4 + 0]);
        accj[q * 4 + 1] = fmaf(a, wj.y, accj[q * 4 + 1]);
        accj[q * 4 + 2] = fmaf(a, wj.z, accj[q * 4 + 2]);
        accj[q * 4 + 3] = fmaf(a, wj.w, accj[q * 4 + 3]);
        acci[q * 4 + 0] = fmaf(c, wi.x, acci[q * 4 + 0]);
        acci[q * 4 + 1] = fmaf(c, wi.y, acci[q * 4 + 1]);
        acci[q * 4 + 2] = fmaf(c, wi.z, acci[q * 4 + 2]);
        acci[q * 4 + 3] = fmaf(c, wi.w, acci[q * 4 + 3]);
      }
    }
#pragma unroll
    for (int d = 0; d < D_; ++d) {
      for (int off = 32; off > 0; off >>= 1) {
        accj[d] += __shfl_down(accj[d], off, 64);
        acci[d] += __shfl_down(acci[d], off, 64);
      }
    }
    if (lane == 0) {
#pragma unroll
      for (int d = 0; d < D_; ++d) {
        Zj[r * D_ + d] = accj[d];
        Zi[r * D_ + d] = acci[d];
      }
    }
  }
}

// ---------------------------------------------------------------------------
// Fused pair-MLP + softmax. One block per j-row (1024 blocks, 256 thr).
// C = Wbig(M=96h) x F(N=keys): lane lo = key, rows = hidden -> relu.W2
// reduce is 24 in-lane FMAs + 2 shfl_xor per key-tile.
// ---------------------------------------------------------------------------
#define FOFFB   0                       // 10*256*16 = 40960
#define WOFFB   40960                   // 1024 chunks * 16 = 16384
#define ZOFFB   (WOFFB + 960*16)        // zero chunk
#define LOGOFFB (WOFFB + 16384)         // 512 f32 logits
#define ZJOFFB  (LOGOFFB + 2048)        // 24 f32
#define W2OFFB  (ZJOFFB + 96)           // 96 f32
#define REDOFFB (W2OFFB + 384)          // 8 f32
#define LDSB    (REDOFFB + 32)

__global__ __launch_bounds__(256) void pair_fused_kernel(
    const float* __restrict__ Zj, const float* __restrict__ Zi,
    const float* __restrict__ W1, const float* __restrict__ b1,
    const float* __restrict__ W2, const _Float16* __restrict__ Wimg,
    const float* __restrict__ mask, _Float16* __restrict__ probs) {
  __shared__ __attribute__((aligned(16))) char smem[LDSB];
  const int t = threadIdx.x;
  const int w = t >> 6, l = t & 63;
  const int lo = l & 15, hi = l >> 4;
  const int rj = blockIdx.x;
  const int b = rj >> 9;

  // stage weight image -> LDS (wave-linear dest)
#pragma unroll
  for (int r = 0; r < 4; ++r) {
    const _Float16* src = Wimg + (size_t)(r * 256 + w * 64 + l) * 8;
    __builtin_amdgcn_global_load_lds(
        (const __attribute__((address_space(1))) void*)src,
        (__attribute__((address_space(3))) void*)(smem + WOFFB + (r * 256 + w * 64) * 16),
        16, 0, 0);
  }
  float* zjL    = (float*)(smem + ZJOFFB);
  float* W2s    = (float*)(smem + W2OFFB);
  float* logits = (float*)(smem + LOGOFFB);
  float* red    = (float*)(smem + REDOFFB);
  if (t < D_) zjL[t] = Zj[(size_t)rj * D_ + t];
  if (t < M_) W2s[t] = W2[t];
  float aj = 0.f;
  if (t < M_) {
    aj = b1[t];
#pragma unroll
    for (int d = 0; d < D_; ++d)
      aj = fmaf(Zj[(size_t)rj * D_ + d], W1[d * M_ + t], aj);
  }
  __syncthreads();   // staging + zjL/W2s visible
  if (t < M_) {
    half8 v = {};
    v[0] = (_Float16)aj;
    *(half8*)(smem + WOFFB + (864 + t) * 16) = v;  // Aj row at K=72
  }

  half8 wf[6][3];
  float w2r[6][4];

  for (int p = 0; p < 2; ++p) {
    // ---- feature build: thread owns key i = p*256 + t ----
    {
      int i = p * 256 + t;
      const float* zi = Zi + (size_t)(b * S_ + i) * D_;
      float ziv[D_];
#pragma unroll
      for (int q = 0; q < 6; ++q) {
        float4 v = ((const float4*)zi)[q];
        ziv[q * 4 + 0] = v.x; ziv[q * 4 + 1] = v.y;
        ziv[q * 4 + 2] = v.z; ziv[q * 4 + 3] = v.w;
      }
#pragma unroll
      for (int kc = 0; kc < 3; ++kc) {
        half8 v;
#pragma unroll
        for (int e = 0; e < 8; ++e) v[e] = (_Float16)ziv[kc * 8 + e];
        *(half8*)(smem + FOFFB + (kc * 256 + t) * 16) = v;
      }
#pragma unroll
      for (int kc = 0; kc < 3; ++kc) {
        half8 v;
#pragma unroll
        for (int e = 0; e < 8; ++e) {
          int d = kc * 8 + e;
          v[e] = (_Float16)(zjL[d] * ziv[d]);
        }
        *(half8*)(smem + FOFFB + ((kc + 3) * 256 + t) * 16) = v;
      }
#pragma unroll
      for (int kc = 0; kc < 3; ++kc) {
        half8 v;
#pragma unroll
        for (int e = 0; e < 8; ++e) {
          int d = kc * 8 + e;
          v[e] = (_Float16)fabsf(zjL[d] - ziv[d]);
        }
        *(half8*)(smem + FOFFB + ((kc + 6) * 256 + t) * 16) = v;
      }
      if (p == 0) {
        half8 v = {};
        v[0] = (_Float16)1.0f;
        *(half8*)(smem + FOFFB + (9 * 256 + t) * 16) = v;
      }
    }
    __syncthreads();

    if (p == 0) {   // cache W fragments + W2 slice in regs (const across passes)
#pragma unroll
      for (int mh = 0; mh < 6; ++mh) {
#pragma unroll
        for (int ks = 0; ks < 3; ++ks) {
          int kc = ks * 4 + hi;
          int off = (kc < 10) ? (WOFFB + (kc * 96 + mh * 16 + lo) * 16) : ZOFFB;
          wf[mh][ks] = *(const half8*)(smem + off);
        }
#pragma unroll
        for (int r = 0; r < 4; ++r) w2r[mh][r] = W2s[mh * 16 + hi * 4 + r];
      }
    }

    // ---- MFMA: wave w owns keys w*64 .. w*64+63 (4 N-tiles) ----
#pragma unroll
    for (int nt = 0; nt < 4; ++nt) {
      half8 ff[3];
#pragma unroll
      for (int ks = 0; ks < 3; ++ks) {
        int kc = ks * 4 + hi;
        int off = (kc < 10) ? (FOFFB + (kc * 256 + w * 64 + nt * 16 + lo) * 16) : ZOFFB;
        ff[ks] = *(const half8*)(smem + off);
      }
      f32x4 a6[6] = {};
#pragma unroll
      for (int ks = 0; ks < 3; ++ks)
#pragma unroll
        for (int mh = 0; mh < 6; ++mh)
          a6[mh] = __builtin_amdgcn_mfma_f32_16x16x32_f16(wf[mh][ks], ff[ks], a6[mh], 0, 0, 0);
      float part = 0.f;
#pragma unroll
      for (int mh = 0; mh < 6; ++mh)
#pragma unroll
        for (int r = 0; r < 4; ++r)
          part = fmaf(fmaxf(a6[mh][r], 0.f), w2r[mh][r], part);
      part += __shfl_xor(part, 16);
      part += __shfl_xor(part, 32);
      if (hi == 0) logits[p * 256 + w * 64 + nt * 16 + lo] = part;
    }
    __syncthreads();
  }

  // ---- masked softmax over 512 keys (b2 dropped: shift-invariant) ----
  float m1 = mask[b * S_ + t], m2 = mask[b * S_ + t + 256];
  float lg1 = logits[t]       + (1.0f - m1) * (-3.40282347e38f);
  float lg2 = logits[t + 256] + (1.0f - m2) * (-3.40282347e38f);
  float mx = fmaxf(lg1, lg2);
#pragma unroll
  for (int off = 32; off > 0; off >>= 1) mx = fmaxf(mx, __shfl_xor(mx, off));
  if (l == 0) red[w] = mx;
  __syncthreads();
  float rmax = fmaxf(fmaxf(red[0], red[1]), fmaxf(red[2], red[3]));
  float e1 = __expf(lg1 - rmax);
  float e2 = __expf(lg2 - rmax);
  float s = e1 + e2;
#pragma unroll
  for (int off = 32; off > 0; off >>= 1) s += __shfl_xor(s, off);
  if (l == 0) red[4 + w] = s;
  __syncthreads();
  float inv = 1.0f / (red[4] + red[5] + red[6] + red[7]);
  probs[(size_t)rj * S_ + t]       = (_Float16)(e1 * inv);
  probs[(size_t)rj * S_ + t + 256] = (_Float16)(e2 * inv);
}

// ---------------------------------------------------------------------------
// fp16 MFMA GEMM, in-block split-K: 512 thr = 2 groups x 4 waves.
// Group g covers K-half g; private 32KB LDS ring (4 x 8KB), depth-3 prefetch,
// counted vmcnt. f32 cross-group reduce via LDS, epilogue by group 0.
// ---------------------------------------------------------------------------
template <bool HASA1, bool RELU, bool FINAL, bool OUTH>
__global__ __launch_bounds__(512) void mfma_gemm_kernel(
    const _Float16* __restrict__ A0, const _Float16* __restrict__ A1,
    const _Float16* __restrict__ Bt, const float* __restrict__ bias,
    const float* __restrict__ alpha_ptr, void* __restrict__ Cout,
    int M, int N, int K0, int K1,
    long aB0, long aB1, long bB, long cB) {
  __shared__ __attribute__((aligned(16))) char smem[65536];
  const int t = threadIdx.x;
  const int w = t >> 6, l = t & 63;
  const int g = w >> 2, wq = w & 3;
  const int K = K0 + K1;
  const int KH = K >> 1;
  const int NT = KH >> 5;
  const int n0 = blockIdx.x * 64, m0 = blockIdx.y * 64;
  const int zb = blockIdx.z;
  const _Float16* A0b = A0 + (size_t)zb * aB0;
  const _Float16* A1b = HASA1 ? (A1 + (size_t)zb * aB1) : nullptr;
  const _Float16* Btb = Bt + (size_t)zb * bB;
  char* gls = smem + (g << 15);

  const int sr = (wq << 4) + (l >> 2);
  const int sk = ((l & 3) ^ ((l >> 3) & 3)) << 3;

  const int mq = wq >> 1, nq = wq & 1;
  int offA[2], offB[2];
#pragma unroll
  for (int i = 0; i < 2; ++i) {
    int ra = mq * 32 + i * 16 + (l & 15);
    offA[i] = ra * 64 + (((l >> 4) ^ ((ra >> 1) & 3)) << 4);
    int rb = nq * 32 + i * 16 + (l & 15);
    offB[i] = 4096 + rb * 64 + (((l >> 4) ^ ((rb >> 1) & 3)) << 4);
  }

  f32x4 acc[2][2] = {};

  auto stage = [&](int tt) {
    char* buf = gls + (tt & 3) * 8192;
    int kg = g * KH + (tt << 5) + sk;
    const _Float16* ga;
    if (HASA1 && kg >= K0) ga = A1b + (size_t)(m0 + sr) * K1 + (kg - K0);
    else                   ga = A0b + (size_t)(m0 + sr) * K0 + kg;
    __builtin_amdgcn_global_load_lds(
        (const __attribute__((address_space(1))) void*)ga,
        (__attribute__((address_space(3))) void*)(buf + (wq << 10)), 16, 0, 0);
    const _Float16* gb = Btb + (size_t)(n0 + sr) * K + kg;
    __builtin_amdgcn_global_load_lds(
        (const __attribute__((address_space(1))) void*)gb,
        (__attribute__((address_space(3))) void*)(buf + 4096 + (wq << 10)), 16, 0, 0);
  };

  stage(0);
  stage(1);
  stage(2);

  for (int tt = 0; tt < NT; ++tt) {
    if (tt + 2 < NT)      asm volatile("s_waitcnt vmcnt(4)" ::: "memory");
    else if (tt + 1 < NT) asm volatile("s_waitcnt vmcnt(2)" ::: "memory");
    else                  asm volatile("s_waitcnt vmcnt(0)" ::: "memory");
    __builtin_amdgcn_s_barrier();
    __builtin_amdgcn_sched_barrier(0);
    const char* buf = gls + (tt & 3) * 8192;
    half8 a0 = *(const half8*)(buf + offA[0]);
    half8 a1 = *(const half8*)(buf + offA[1]);
    half8 b0 = *(const half8*)(buf + offB[0]);
    half8 b1v = *(const half8*)(buf + offB[1]);
    acc[0][0] = __builtin_amdgcn_mfma_f32_16x16x32_f16(a0, b0, acc[0][0], 0, 0, 0);
    acc[0][1] = __builtin_amdgcn_mfma_f32_16x16x32_f16(a0, b1v, acc[0][1], 0, 0, 0);
    acc[1][0] = __builtin_amdgcn_mfma_f32_16x16x32_f16(a1, b0, acc[1][0], 0, 0, 0);
    acc[1][1] = __builtin_amdgcn_mfma_f32_16x16x32_f16(a1, b1v, acc[1][1], 0, 0, 0);
    if (tt + 3 < NT) stage(tt + 3);
  }

  // cross-group K reduction through LDS (overlays group-0 ring, now dead)
  const int lr = l & 15, lq = l >> 4;
  float* redm = (float*)smem;   // [64][68]
  __syncthreads();
  if (g == 1) {
#pragma unroll
    for (int mi = 0; mi < 2; ++mi)
#pragma unroll
      for (int ni = 0; ni < 2; ++ni)
#pragma unroll
        for (int rg = 0; rg < 4; ++rg)
          redm[(mq * 32 + mi * 16 + lq * 4 + rg) * 68 + nq * 32 + ni * 16 + lr] =
              acc[mi][ni][rg];
  }
  __syncthreads();
  if (g == 0) {
    const float alpha = FINAL ? *alpha_ptr : 1.0f;
    const size_t cbase = (size_t)zb * cB;
#pragma unroll
    for (int mi = 0; mi < 2; ++mi)
#pragma unroll
      for (int ni = 0; ni < 2; ++ni) {
        int col = n0 + nq * 32 + ni * 16 + lr;
        float bv = bias ? bias[col] : 0.0f;
#pragma unroll
        for (int rg = 0; rg < 4; ++rg) {
          int row = m0 + mq * 32 + mi * 16 + lq * 4 + rg;
          float x = acc[mi][ni][rg] +
                    redm[(mq * 32 + mi * 16 + lq * 4 + rg) * 68 + nq * 32 + ni * 16 + lr] +
                    bv;
          if (RELU) x = fmaxf(x, 0.f);
          if (FINAL) x *= alpha;
          if (OUTH)
            ((_Float16*)Cout)[cbase + (size_t)row * N + col] = (_Float16)x;
          else
            ((float*)Cout)[cbase + (size_t)row * N + col] = x;
        }
      }
  }
}

// ---------------------------------------------------------------------------
extern "C" void kernel_launch(void* const* d_in, const int* in_sizes, int n_in,
                              void* d_out, int out_size, void* d_ws, size_t ws_size,
                              hipStream_t stream) {
  const float* Hj   = (const float*)d_in[0];
  const float* Hi   = (const float*)d_in[1];
  const float* mask = (const float*)d_in[2];
  const float* pj   = (const float*)d_in[3];
  const float* pi   = (const float*)d_in[4];
  const float* W1   = (const float*)d_in[5];
  const float* b1   = (const float*)d_in[6];
  const float* W2   = (const float*)d_in[7];
  // d_in[8] = b2: uniform over keys -> softmax invariant, unused
  const float* Wv1  = (const float*)d_in[9];
  const float* bv1  = (const float*)d_in[10];
  const float* Wv2  = (const float*)d_in[11];
  const float* bv2  = (const float*)d_in[12];
  const float* alpha = (const float*)d_in[13];

  char* w = (char*)d_ws;
  float* Zj  = (float*)w;            w += (size_t)ROWS * D_ * 4;
  float* Zi  = (float*)w;            w += (size_t)ROWS * D_ * 4;
  _Float16* Wimg   = (_Float16*)w;   w += (size_t)1024 * 16;
  _Float16* probsH = (_Float16*)w;   w += (size_t)B_ * S_ * S_ * 2;
  _Float16* HjH    = (_Float16*)w;   w += (size_t)ROWS * HDIM * 2;
  _Float16* HiT    = (_Float16*)w;   w += (size_t)B_ * HDIM * S_ * 2;
  _Float16* Wv1T   = (_Float16*)w;   w += (size_t)HDIM * 2 * HDIM * 2;
  _Float16* Wv2T   = (_Float16*)w;   w += (size_t)HDIM * HDIM * 2;
  _Float16* ctxH   = (_Float16*)w;   w += (size_t)ROWS * HDIM * 2;
  _Float16* hidH   = (_Float16*)w;   w += (size_t)ROWS * HDIM * 2;
  float* out = (float*)d_out;

  // all dtype prep + projections in one launch
  prep_kernel<<<5380, 256, 0, stream>>>(Hj, Hi, pj, pi, W1, Wv1, Wv2,
                                        HjH, HiT, Wv1T, Wv2T, Wimg, Zj, Zi);

  pair_fused_kernel<<<ROWS, 256, 0, stream>>>(Zj, Zi, W1, b1, W2, Wimg,
                                              mask, probsH);

  // ctx[b] = probs[b] @ Hi[b]   (M=512, N=1024, K=512) -> fp16
  mfma_gemm_kernel<false, false, false, true><<<dim3(16, 8, 2), 512, 0, stream>>>(
      probsH, nullptr, HiT, nullptr, nullptr, ctxH,
      S_, HDIM, S_, 0, (long)S_ * S_, 0, (long)HDIM * S_, (long)S_ * HDIM);
  // hidden = relu([ctx | Hj] @ Wv1 + bv1)   (M=1024, N=1024, K=2048) -> fp16
  mfma_gemm_kernel<true, true, false, true><<<dim3(16, 16, 1), 512, 0, stream>>>(
      ctxH, HjH, Wv1T, bv1, nullptr, hidH,
      ROWS, HDIM, HDIM, HDIM, 0, 0, 0, 0);
  // out = alpha * (hidden @ Wv2 + bv2)      (M=1024, N=1024, K=1024) -> fp32
  mfma_gemm_kernel<false, false, true, false><<<dim3(16, 16, 1), 512, 0, stream>>>(
      hidH, nullptr, Wv2T, bv2, alpha, out,
      ROWS, HDIM, HDIM, 0, 0, 0, 0, 0);
}